// Round 1
// baseline (446.541 us; speedup 1.0000x reference)
//
#include <hip/hip_runtime.h>

typedef unsigned short u16;
typedef __attribute__((ext_vector_type(8))) short bf16x8;
typedef __attribute__((ext_vector_type(4))) float f32x4;

#define SEQ 4096
#define DIM 1024

// ---------- bf16 helpers (OCP bf16 = top 16 bits of fp32, RNE) ----------
__device__ __forceinline__ u16 f2bf(float f) {
  unsigned u = __float_as_uint(f);
  return (u16)((u + 0x7fffu + ((u >> 16) & 1u)) >> 16);
}
__device__ __forceinline__ float bf2f(u16 h) {
  return __uint_as_float(((unsigned)h) << 16);
}

// ---------- async global->LDS, 16B per lane ----------
__device__ __forceinline__ void gload_lds16(const void* g, void* l) {
  __builtin_amdgcn_global_load_lds(
      (const __attribute__((address_space(1))) void*)g,
      (__attribute__((address_space(3))) void*)l, 16, 0, 0);
}

// stage a 128x32 bf16 tile (row-major, leading dim ld elems) into LDS [128][32]
// LDS dest must be wave-uniform base + lane*16 (m104/m108), so chunk c = it*256+tid
// maps LDS offset c*16B <-> global row c/4, col-chunk (c%4)*8 elems.
__device__ __forceinline__ void stage_tile(const u16* __restrict__ g, int ld,
                                           u16* lds, int tid) {
  const int w = tid >> 6;
#pragma unroll
  for (int it = 0; it < 2; ++it) {
    int c = it * 256 + tid;
    int row = c >> 2, ch = c & 3;
    gload_lds16(g + (size_t)row * ld + ch * 8, lds + (size_t)(it * 256 + w * 64) * 8);
  }
}

// ---------- NT GEMM core: C[128,128] += sum_p A_p[128,K] * B_p[128,K]^T ----------
// 4 waves in 2x2; each wave 64x64 as 4x4 of 16x16x32 MFMA.
// A-frag: lane holds A[m=lane&15][k=(lane>>4)*8+j]; B-frag symmetric.
template <int NP>
__device__ __forceinline__ void gemm_core(
    const u16* A0, const u16* A1, const u16* A2,
    const u16* B0, const u16* B1, const u16* B2,
    int K, int ldA, int ldB,
    u16* lA, u16* lB, f32x4 (&acc)[4][4]) {
  const int tid = threadIdx.x;
  const int w = tid >> 6, l = tid & 63;
  const int wm = w >> 1, wn = w & 1;
  const int lr = l & 15, q = l >> 4;

  const u16* As[3] = {A0, A1, A2};
  const u16* Bs[3] = {B0, B1, B2};

#pragma unroll
  for (int mi = 0; mi < 4; ++mi)
#pragma unroll
    for (int ni = 0; ni < 4; ++ni)
      acc[mi][ni] = (f32x4){0.f, 0.f, 0.f, 0.f};

#pragma unroll
  for (int p = 0; p < NP; ++p) {
    const u16* A = As[p];
    const u16* B = Bs[p];
    for (int k0 = 0; k0 < K; k0 += 32) {
      stage_tile(A + k0, ldA, lA, tid);
      stage_tile(B + k0, ldB, lB, tid);
      __syncthreads();
      bf16x8 av[4], bv[4];
      const u16* ap = lA + (wm * 64 + lr) * 32 + q * 8;
      const u16* bp = lB + (wn * 64 + lr) * 32 + q * 8;
#pragma unroll
      for (int i = 0; i < 4; ++i) {
        av[i] = *(const bf16x8*)(ap + i * 16 * 32);
        bv[i] = *(const bf16x8*)(bp + i * 16 * 32);
      }
#pragma unroll
      for (int mi = 0; mi < 4; ++mi)
#pragma unroll
        for (int ni = 0; ni < 4; ++ni)
          acc[mi][ni] = __builtin_amdgcn_mfma_f32_16x16x32_bf16(
              av[mi], bv[ni], acc[mi][ni], 0, 0, 0);
      __syncthreads();
    }
  }
}

// C/D layout (m89/m91 verified): lane l, reg r -> row=(l>>4)*4+r, col=l&15
#define EPILOGUE_IDX                                    \
  const int tid = threadIdx.x, w = tid >> 6, l = tid & 63; \
  const int wm = w >> 1, wn = w & 1, lr = l & 15, q = l >> 4;

// ---------- kernels ----------

// X fp32 -> hi/lo bf16 split (elementwise, float4)
__global__ __launch_bounds__(256) void split_x_kernel(const float* __restrict__ X,
                                                      u16* __restrict__ Xh,
                                                      u16* __restrict__ Xl) {
  int i = (blockIdx.x * 256 + threadIdx.x) * 4;
  float4 x = *(const float4*)(X + i);
  ushort4 h, lo;
  float v;
  v = x.x; h.x = f2bf(v); lo.x = f2bf(v - bf2f(h.x));
  v = x.y; h.y = f2bf(v); lo.y = f2bf(v - bf2f(h.y));
  v = x.z; h.z = f2bf(v); lo.z = f2bf(v - bf2f(h.z));
  v = x.w; h.w = f2bf(v); lo.w = f2bf(v - bf2f(h.w));
  *(ushort4*)(Xh + i) = h;
  *(ushort4*)(Xl + i) = lo;
}

// W [1024][1024] fp32 (in,out) -> transposed hi/lo bf16 [out][in], tiled via LDS
__global__ __launch_bounds__(256) void split_w_t_kernel(
    const float* __restrict__ W0, const float* __restrict__ W1, const float* __restrict__ W2,
    u16* __restrict__ H0, u16* __restrict__ L0,
    u16* __restrict__ H1, u16* __restrict__ L1,
    u16* __restrict__ H2, u16* __restrict__ L2) {
  __shared__ float t[32][33];
  const int z = blockIdx.z;
  const float* W = (z == 0) ? W0 : (z == 1) ? W1 : W2;
  u16* H = (z == 0) ? H0 : (z == 1) ? H1 : H2;
  u16* L = (z == 0) ? L0 : (z == 1) ? L1 : L2;
  const int i0 = blockIdx.y * 32, o0 = blockIdx.x * 32;
  const int tx = threadIdx.x, ty = threadIdx.y;
#pragma unroll
  for (int m = 0; m < 4; ++m)
    t[ty + 8 * m][tx] = W[(size_t)(i0 + ty + 8 * m) * DIM + o0 + tx];
  __syncthreads();
#pragma unroll
  for (int m = 0; m < 4; ++m) {
    float v = t[tx][ty + 8 * m];
    u16 h = f2bf(v);
    size_t o = (size_t)(o0 + ty + 8 * m) * DIM + i0 + tx;
    H[o] = h;
    L[o] = f2bf(v - bf2f(h));
  }
}

// QKV GEMM: z=0 Q (split out), z=1 K (split out), z=2 V (bf16 out)
__global__ __launch_bounds__(256) void qkv_kernel(
    const u16* __restrict__ Xh, const u16* __restrict__ Xl,
    const u16* __restrict__ Wh0, const u16* __restrict__ Wl0,
    const u16* __restrict__ Wh1, const u16* __restrict__ Wl1,
    const u16* __restrict__ Wh2, const u16* __restrict__ Wl2,
    u16* __restrict__ Qh, u16* __restrict__ Ql,
    u16* __restrict__ Kh, u16* __restrict__ Kl,
    u16* __restrict__ V) {
  __shared__ __align__(16) u16 lA[128 * 32];
  __shared__ __align__(16) u16 lB[128 * 32];
  const int z = blockIdx.z;
  const u16* Wh = (z == 0) ? Wh0 : (z == 1) ? Wh1 : Wh2;
  const u16* Wl = (z == 0) ? Wl0 : (z == 1) ? Wl1 : Wl2;
  const int row0 = blockIdx.y * 128, col0 = blockIdx.x * 128;
  const u16* Ah = Xh + (size_t)row0 * DIM;
  const u16* Al = Xl + (size_t)row0 * DIM;
  const u16* Bh = Wh + (size_t)col0 * DIM;
  const u16* Bl = Wl + (size_t)col0 * DIM;
  f32x4 acc[4][4];
  gemm_core<3>(Ah, Ah, Al, Bh, Bl, Bh, DIM, DIM, DIM, lA, lB, acc);

  EPILOGUE_IDX
  if (z < 2) {
    u16* H = z ? Kh : Qh;
    u16* L = z ? Kl : Ql;
#pragma unroll
    for (int mi = 0; mi < 4; ++mi)
#pragma unroll
      for (int ni = 0; ni < 4; ++ni)
#pragma unroll
        for (int r = 0; r < 4; ++r) {
          int row = row0 + wm * 64 + mi * 16 + q * 4 + r;
          int col = col0 + wn * 64 + ni * 16 + lr;
          float v = acc[mi][ni][r];
          u16 h = f2bf(v);
          size_t o = (size_t)row * DIM + col;
          H[o] = h;
          L[o] = f2bf(v - bf2f(h));
        }
  } else {
#pragma unroll
    for (int mi = 0; mi < 4; ++mi)
#pragma unroll
      for (int ni = 0; ni < 4; ++ni)
#pragma unroll
        for (int r = 0; r < 4; ++r) {
          int row = row0 + wm * 64 + mi * 16 + q * 4 + r;
          int col = col0 + wn * 64 + ni * 16 + lr;
          V[(size_t)row * DIM + col] = f2bf(acc[mi][ni][r]);
        }
  }
}

// V bf16 [4096][1024] -> VT bf16 [1024][4096]
__global__ __launch_bounds__(256) void transpose_v_kernel(const u16* __restrict__ V,
                                                          u16* __restrict__ VT) {
  __shared__ u16 t[32][33];
  const int s0 = blockIdx.y * 32, o0 = blockIdx.x * 32;
  const int tx = threadIdx.x, ty = threadIdx.y;
#pragma unroll
  for (int m = 0; m < 4; ++m)
    t[ty + 8 * m][tx] = V[(size_t)(s0 + ty + 8 * m) * DIM + o0 + tx];
  __syncthreads();
#pragma unroll
  for (int m = 0; m < 4; ++m)
    VT[(size_t)(o0 + ty + 8 * m) * SEQ + s0 + tx] = t[tx][ty + 8 * m];
}

// S = (Q K^T) * 1/32, split-precision 3-pass, fp32 out
__global__ __launch_bounds__(256) void s_kernel(
    const u16* __restrict__ Qh, const u16* __restrict__ Ql,
    const u16* __restrict__ Kh, const u16* __restrict__ Kl,
    float* __restrict__ S) {
  __shared__ __align__(16) u16 lA[128 * 32];
  __shared__ __align__(16) u16 lB[128 * 32];
  const int row0 = blockIdx.y * 128, col0 = blockIdx.x * 128;
  const u16* Aq = Qh + (size_t)row0 * DIM;
  const u16* Aql = Ql + (size_t)row0 * DIM;
  const u16* Bk = Kh + (size_t)col0 * DIM;
  const u16* Bkl = Kl + (size_t)col0 * DIM;
  f32x4 acc[4][4];
  gemm_core<3>(Aq, Aq, Aql, Bk, Bkl, Bk, DIM, DIM, DIM, lA, lB, acc);

  EPILOGUE_IDX
  const float scale = 0.03125f;  // 1/sqrt(1024)
#pragma unroll
  for (int mi = 0; mi < 4; ++mi)
#pragma unroll
    for (int ni = 0; ni < 4; ++ni)
#pragma unroll
      for (int r = 0; r < 4; ++r) {
        int row = row0 + wm * 64 + mi * 16 + q * 4 + r;
        int col = col0 + wn * 64 + ni * 16 + lr;
        S[(size_t)row * SEQ + col] = acc[mi][ni][r] * scale;
      }
}

// row softmax: S fp32 [4096][4096] -> P bf16
__global__ __launch_bounds__(256) void softmax_kernel(const float* __restrict__ S,
                                                      u16* __restrict__ P) {
  const int row = blockIdx.x;
  const float* s = S + (size_t)row * SEQ;
  const int tid = threadIdx.x;
  float v[16];
  float mx = -3.4e38f;
#pragma unroll
  for (int i = 0; i < 16; ++i) {
    v[i] = s[tid + i * 256];
    mx = fmaxf(mx, v[i]);
  }
#pragma unroll
  for (int off = 32; off; off >>= 1) mx = fmaxf(mx, __shfl_xor(mx, off));
  __shared__ float red[8];
  const int w = tid >> 6, l = tid & 63;
  if (l == 0) red[w] = mx;
  __syncthreads();
  mx = fmaxf(fmaxf(red[0], red[1]), fmaxf(red[2], red[3]));
  float sum = 0.f;
#pragma unroll
  for (int i = 0; i < 16; ++i) {
    v[i] = __expf(v[i] - mx);
    sum += v[i];
  }
#pragma unroll
  for (int off = 32; off; off >>= 1) sum += __shfl_xor(sum, off);
  if (l == 0) red[4 + w] = sum;
  __syncthreads();
  sum = red[4] + red[5] + red[6] + red[7];
  const float inv = 1.f / sum;
  u16* p = P + (size_t)row * SEQ;
#pragma unroll
  for (int i = 0; i < 16; ++i) p[tid + i * 256] = f2bf(v[i] * inv);
}

// O = P @ V  (NT with B = VT), fp32 out
__global__ __launch_bounds__(256) void o_kernel(const u16* __restrict__ P,
                                                const u16* __restrict__ VT,
                                                float* __restrict__ O) {
  __shared__ __align__(16) u16 lA[128 * 32];
  __shared__ __align__(16) u16 lB[128 * 32];
  const int row0 = blockIdx.y * 128, col0 = blockIdx.x * 128;
  const u16* A = P + (size_t)row0 * SEQ;
  const u16* B = VT + (size_t)col0 * SEQ;
  f32x4 acc[4][4];
  gemm_core<1>(A, A, A, B, B, B, SEQ, SEQ, SEQ, lA, lB, acc);

  EPILOGUE_IDX
#pragma unroll
  for (int mi = 0; mi < 4; ++mi)
#pragma unroll
    for (int ni = 0; ni < 4; ++ni)
#pragma unroll
      for (int r = 0; r < 4; ++r) {
        int row = row0 + wm * 64 + mi * 16 + q * 4 + r;
        int col = col0 + wn * 64 + ni * 16 + lr;
        O[(size_t)row * DIM + col] = acc[mi][ni][r];
      }
}

// ---------- launch ----------
extern "C" void kernel_launch(void* const* d_in, const int* in_sizes, int n_in,
                              void* d_out, int out_size, void* d_ws, size_t ws_size,
                              hipStream_t stream) {
  const float* X = (const float*)d_in[0];
  const float* Wq = (const float*)d_in[1];
  const float* Wk = (const float*)d_in[2];
  const float* Wv = (const float*)d_in[3];

  const size_t MB = 1024 * 1024;
  char* w = (char*)d_ws;
  u16* Xh = (u16*)(w + 0 * MB);
  u16* Xl = (u16*)(w + 8 * MB);
  u16* WqhT = (u16*)(w + 16 * MB);
  u16* WqlT = (u16*)(w + 18 * MB);
  u16* WkhT = (u16*)(w + 20 * MB);
  u16* WklT = (u16*)(w + 22 * MB);
  u16* WvhT = (u16*)(w + 24 * MB);
  u16* WvlT = (u16*)(w + 26 * MB);
  u16* Qh = (u16*)(w + 28 * MB);
  u16* Ql = (u16*)(w + 36 * MB);
  u16* Kh = (u16*)(w + 44 * MB);
  u16* Kl = (u16*)(w + 52 * MB);
  u16* V = (u16*)(w + 60 * MB);
  u16* VT = (u16*)(w + 68 * MB);
  float* S = (float*)(w + 76 * MB);       // 64 MB
  u16* P = (u16*)(w + 28 * MB);           // aliases Qh..Kl (dead after s_kernel)

  // 1. split X -> hi/lo bf16
  split_x_kernel<<<(SEQ * DIM) / (256 * 4), 256, 0, stream>>>(X, Xh, Xl);
  // 2. split + transpose W's
  split_w_t_kernel<<<dim3(32, 32, 3), dim3(32, 8), 0, stream>>>(
      Wq, Wk, Wv, WqhT, WqlT, WkhT, WklT, WvhT, WvlT);
  // 3. Q,K,V GEMMs (split precision)
  qkv_kernel<<<dim3(DIM / 128, SEQ / 128, 3), 256, 0, stream>>>(
      Xh, Xl, WqhT, WqlT, WkhT, WklT, WvhT, WvlT, Qh, Ql, Kh, Kl, V);
  // 4. V transpose for NT O-GEMM
  transpose_v_kernel<<<dim3(DIM / 32, SEQ / 32), dim3(32, 8), 0, stream>>>(V, VT);
  // 5. S = Q K^T / 32 (split precision)
  s_kernel<<<dim3(SEQ / 128, SEQ / 128), 256, 0, stream>>>(Qh, Ql, Kh, Kl, S);
  // 6. softmax rows -> P bf16
  softmax_kernel<<<SEQ, 256, 0, stream>>>(S, P);
  // 7. O = P V
  o_kernel<<<dim3(DIM / 128, SEQ / 128), 256, 0, stream>>>(P, VT, (float*)d_out);
}

// Round 2
// 336.736 us; speedup vs baseline: 1.3261x; 1.3261x over previous
//
#include <hip/hip_runtime.h>

typedef unsigned short u16;
typedef __attribute__((ext_vector_type(8))) short bf16x8;
typedef __attribute__((ext_vector_type(4))) float f32x4;

#define SEQ 4096
#define DIM 1024

// ---------- bf16 helpers (OCP bf16 = top 16 bits of fp32, RNE) ----------
__device__ __forceinline__ u16 f2bf(float f) {
  unsigned u = __float_as_uint(f);
  return (u16)((u + 0x7fffu + ((u >> 16) & 1u)) >> 16);
}
__device__ __forceinline__ float bf2f(u16 h) {
  return __uint_as_float(((unsigned)h) << 16);
}

// ---------- async global->LDS, 16B per lane ----------
__device__ __forceinline__ void gload_lds16(const void* g, void* l) {
  __builtin_amdgcn_global_load_lds(
      (const __attribute__((address_space(1))) void*)g,
      (__attribute__((address_space(3))) void*)l, 16, 0, 0);
}

// stage a 128x32 bf16 tile (row-major, leading dim ld elems) into LDS [128][32]
// LDS dest is wave-uniform base + lane*16 (m104/m108): chunk c = it*256+tid
// maps LDS offset c*16B <-> global row c/4, col-chunk (c%4)*8 elems.
__device__ __forceinline__ void stage_tile(const u16* __restrict__ g, int ld,
                                           u16* lds, int tid) {
  const int w = tid >> 6;
#pragma unroll
  for (int it = 0; it < 2; ++it) {
    int c = it * 256 + tid;
    int row = c >> 2, ch = c & 3;
    gload_lds16(g + (size_t)row * ld + ch * 8, lds + (size_t)(it * 256 + w * 64) * 8);
  }
}

// ---------- fused multi-pair NT GEMM core ----------
// C[128,128] += A0*B0^T  (+ A0*B1^T + A1*B0^T for NPAIR==3)
// All operand tiles staged ONCE per k0; 16/48 MFMA per barrier pair.
// 4 waves in 2x2; each wave 64x64 as 4x4 of 16x16x32 MFMA.
template <int NPAIR>
__device__ __forceinline__ void gemm_multi(
    const u16* A0, const u16* A1,
    const u16* B0, const u16* B1,
    int K, int ldA, int ldB,
    u16* lds, f32x4 (&acc)[4][4]) {
  const int tid = threadIdx.x;
  const int w = tid >> 6, l = tid & 63;
  const int wm = w >> 1, wn = w & 1;
  const int lr = l & 15, q = l >> 4;
  u16* lA0 = lds;
  u16* lB0 = lds + 4096;
  u16* lA1 = lds + 8192;
  u16* lB1 = lds + 12288;

#pragma unroll
  for (int mi = 0; mi < 4; ++mi)
#pragma unroll
    for (int ni = 0; ni < 4; ++ni)
      acc[mi][ni] = (f32x4){0.f, 0.f, 0.f, 0.f};

  const int ao = (wm * 64 + lr) * 32 + q * 8;
  const int bo = (wn * 64 + lr) * 32 + q * 8;

  for (int k0 = 0; k0 < K; k0 += 32) {
    stage_tile(A0 + k0, ldA, lA0, tid);
    stage_tile(B0 + k0, ldB, lB0, tid);
    if constexpr (NPAIR >= 3) {
      stage_tile(A1 + k0, ldA, lA1, tid);
      stage_tile(B1 + k0, ldB, lB1, tid);
    }
    __syncthreads();
    bf16x8 a0[4], b0[4];
#pragma unroll
    for (int i = 0; i < 4; ++i) {
      a0[i] = *(const bf16x8*)(lA0 + ao + i * 512);
      b0[i] = *(const bf16x8*)(lB0 + bo + i * 512);
    }
#pragma unroll
    for (int mi = 0; mi < 4; ++mi)
#pragma unroll
      for (int ni = 0; ni < 4; ++ni)
        acc[mi][ni] = __builtin_amdgcn_mfma_f32_16x16x32_bf16(
            a0[mi], b0[ni], acc[mi][ni], 0, 0, 0);
    if constexpr (NPAIR >= 3) {
      bf16x8 b1[4];
#pragma unroll
      for (int i = 0; i < 4; ++i) b1[i] = *(const bf16x8*)(lB1 + bo + i * 512);
#pragma unroll
      for (int mi = 0; mi < 4; ++mi)
#pragma unroll
        for (int ni = 0; ni < 4; ++ni)
          acc[mi][ni] = __builtin_amdgcn_mfma_f32_16x16x32_bf16(
              a0[mi], b1[ni], acc[mi][ni], 0, 0, 0);
      bf16x8 a1[4];
#pragma unroll
      for (int i = 0; i < 4; ++i) a1[i] = *(const bf16x8*)(lA1 + ao + i * 512);
#pragma unroll
      for (int mi = 0; mi < 4; ++mi)
#pragma unroll
        for (int ni = 0; ni < 4; ++ni)
          acc[mi][ni] = __builtin_amdgcn_mfma_f32_16x16x32_bf16(
              a1[mi], b0[ni], acc[mi][ni], 0, 0, 0);
    }
    __syncthreads();
  }
}

// C/D layout (m89/m91 verified): lane l, reg r -> row=(l>>4)*4+r, col=l&15
#define EPILOGUE_IDX                                          \
  const int tid = threadIdx.x, w = tid >> 6, l = tid & 63;    \
  const int wm = w >> 1, wn = w & 1, lr = l & 15, q = l >> 4; \
  (void)tid;

// ---------- kernels ----------

// X fp32 -> hi/lo bf16 split (elementwise, float4)
__global__ __launch_bounds__(256) void split_x_kernel(const float* __restrict__ X,
                                                      u16* __restrict__ Xh,
                                                      u16* __restrict__ Xl) {
  int i = (blockIdx.x * 256 + threadIdx.x) * 4;
  float4 x = *(const float4*)(X + i);
  ushort4 h, lo;
  float v;
  v = x.x; h.x = f2bf(v); lo.x = f2bf(v - bf2f(h.x));
  v = x.y; h.y = f2bf(v); lo.y = f2bf(v - bf2f(h.y));
  v = x.z; h.z = f2bf(v); lo.z = f2bf(v - bf2f(h.z));
  v = x.w; h.w = f2bf(v); lo.w = f2bf(v - bf2f(h.w));
  *(ushort4*)(Xh + i) = h;
  *(ushort4*)(Xl + i) = lo;
}

// W [1024][1024] fp32 (in,out) -> transposed bf16 [out][in]; hi/lo for Wq,Wk, hi-only for Wv
__global__ __launch_bounds__(256) void split_w_t_kernel(
    const float* __restrict__ W0, const float* __restrict__ W1, const float* __restrict__ W2,
    u16* __restrict__ H0, u16* __restrict__ L0,
    u16* __restrict__ H1, u16* __restrict__ L1,
    u16* __restrict__ H2) {
  __shared__ float t[32][33];
  const int z = blockIdx.z;
  const float* W = (z == 0) ? W0 : (z == 1) ? W1 : W2;
  u16* H = (z == 0) ? H0 : (z == 1) ? H1 : H2;
  u16* L = (z == 0) ? L0 : (z == 1) ? L1 : nullptr;
  const int i0 = blockIdx.y * 32, o0 = blockIdx.x * 32;
  const int tx = threadIdx.x, ty = threadIdx.y;
#pragma unroll
  for (int m = 0; m < 4; ++m)
    t[ty + 8 * m][tx] = W[(size_t)(i0 + ty + 8 * m) * DIM + o0 + tx];
  __syncthreads();
#pragma unroll
  for (int m = 0; m < 4; ++m) {
    float v = t[tx][ty + 8 * m];
    u16 h = f2bf(v);
    size_t o = (size_t)(o0 + ty + 8 * m) * DIM + i0 + tx;
    H[o] = h;
    if (L) L[o] = f2bf(v - bf2f(h));
  }
}

// z=0: Q = X Wq (split-precision, split out)  z=1: K likewise
// z=2: VT = Wv^T X^T (single-pass bf16, written directly transposed [DIM][SEQ])
__global__ __launch_bounds__(256) void qkv_kernel(
    const u16* __restrict__ Xh, const u16* __restrict__ Xl,
    const u16* __restrict__ Wh0, const u16* __restrict__ Wl0,
    const u16* __restrict__ Wh1, const u16* __restrict__ Wl1,
    const u16* __restrict__ Wh2,
    u16* __restrict__ Qh, u16* __restrict__ Ql,
    u16* __restrict__ Kh, u16* __restrict__ Kl,
    u16* __restrict__ VT) {
  __shared__ __align__(16) u16 lds[4 * 4096];
  const int z = blockIdx.z;
  f32x4 acc[4][4];
  if (z < 2) {
    const u16* Wh = z ? Wh1 : Wh0;
    const u16* Wl = z ? Wl1 : Wl0;
    const int row0 = blockIdx.y * 128, col0 = blockIdx.x * 128;
    gemm_multi<3>(Xh + (size_t)row0 * DIM, Xl + (size_t)row0 * DIM,
                  Wh + (size_t)col0 * DIM, Wl + (size_t)col0 * DIM,
                  DIM, DIM, DIM, lds, acc);
    EPILOGUE_IDX
    u16* H = z ? Kh : Qh;
    u16* L = z ? Kl : Ql;
#pragma unroll
    for (int mi = 0; mi < 4; ++mi)
#pragma unroll
      for (int ni = 0; ni < 4; ++ni)
#pragma unroll
        for (int r = 0; r < 4; ++r) {
          int row = row0 + wm * 64 + mi * 16 + q * 4 + r;
          int col = col0 + wn * 64 + ni * 16 + lr;
          float v = acc[mi][ni][r];
          u16 h = f2bf(v);
          size_t o = (size_t)row * DIM + col;
          H[o] = h;
          L[o] = f2bf(v - bf2f(h));
        }
  } else {
    const int row0 = blockIdx.x * 128;  // over DIM
    const int col0 = blockIdx.y * 128;  // over SEQ
    gemm_multi<1>(Wh2 + (size_t)row0 * DIM, nullptr,
                  Xh + (size_t)col0 * DIM, nullptr,
                  DIM, DIM, DIM, lds, acc);
    EPILOGUE_IDX
#pragma unroll
    for (int mi = 0; mi < 4; ++mi)
#pragma unroll
      for (int ni = 0; ni < 4; ++ni)
#pragma unroll
        for (int r = 0; r < 4; ++r) {
          int row = row0 + wm * 64 + mi * 16 + q * 4 + r;
          int col = col0 + wn * 64 + ni * 16 + lr;
          VT[(size_t)row * SEQ + col] = f2bf(acc[mi][ni][r]);
        }
  }
}

// S = (Q K^T) * 1/32, split-precision fused 3-pair, fp32 out
__global__ __launch_bounds__(256) void s_kernel(
    const u16* __restrict__ Qh, const u16* __restrict__ Ql,
    const u16* __restrict__ Kh, const u16* __restrict__ Kl,
    float* __restrict__ S) {
  __shared__ __align__(16) u16 lds[4 * 4096];
  const int row0 = blockIdx.y * 128, col0 = blockIdx.x * 128;
  f32x4 acc[4][4];
  gemm_multi<3>(Qh + (size_t)row0 * DIM, Ql + (size_t)row0 * DIM,
                Kh + (size_t)col0 * DIM, Kl + (size_t)col0 * DIM,
                DIM, DIM, DIM, lds, acc);
  EPILOGUE_IDX
  const float scale = 0.03125f;  // 1/sqrt(1024)
#pragma unroll
  for (int mi = 0; mi < 4; ++mi)
#pragma unroll
    for (int ni = 0; ni < 4; ++ni)
#pragma unroll
      for (int r = 0; r < 4; ++r) {
        int row = row0 + wm * 64 + mi * 16 + q * 4 + r;
        int col = col0 + wn * 64 + ni * 16 + lr;
        S[(size_t)row * SEQ + col] = acc[mi][ni][r] * scale;
      }
}

// row softmax: S fp32 [4096][4096] -> P bf16
__global__ __launch_bounds__(256) void softmax_kernel(const float* __restrict__ S,
                                                      u16* __restrict__ P) {
  const int row = blockIdx.x;
  const float* s = S + (size_t)row * SEQ;
  const int tid = threadIdx.x;
  float v[16];
  float mx = -3.4e38f;
#pragma unroll
  for (int i = 0; i < 16; ++i) {
    v[i] = s[tid + i * 256];
    mx = fmaxf(mx, v[i]);
  }
#pragma unroll
  for (int off = 32; off; off >>= 1) mx = fmaxf(mx, __shfl_xor(mx, off));
  __shared__ float red[8];
  const int w = tid >> 6, l = tid & 63;
  if (l == 0) red[w] = mx;
  __syncthreads();
  mx = fmaxf(fmaxf(red[0], red[1]), fmaxf(red[2], red[3]));
  float sum = 0.f;
#pragma unroll
  for (int i = 0; i < 16; ++i) {
    v[i] = __expf(v[i] - mx);
    sum += v[i];
  }
#pragma unroll
  for (int off = 32; off; off >>= 1) sum += __shfl_xor(sum, off);
  if (l == 0) red[4 + w] = sum;
  __syncthreads();
  sum = red[4] + red[5] + red[6] + red[7];
  const float inv = 1.f / sum;
  u16* p = P + (size_t)row * SEQ;
#pragma unroll
  for (int i = 0; i < 16; ++i) p[tid + i * 256] = f2bf(v[i] * inv);
}

// O partial = P[:, z*1024:(z+1)*1024] @ V[z*1024:(z+1)*1024, :]  (split-K=4)
__global__ __launch_bounds__(256) void o_kernel(const u16* __restrict__ P,
                                                const u16* __restrict__ VT,
                                                float* __restrict__ Opart) {
  __shared__ __align__(16) u16 lds[2 * 4096];
  const int z = blockIdx.z;
  const int row0 = blockIdx.y * 128, col0 = blockIdx.x * 128;
  const u16* A = P + (size_t)row0 * SEQ + z * 1024;
  const u16* B = VT + (size_t)col0 * SEQ + z * 1024;
  f32x4 acc[4][4];
  gemm_multi<1>(A, nullptr, B, nullptr, 1024, SEQ, SEQ, lds, acc);
  EPILOGUE_IDX
  float* O = Opart + (size_t)z * SEQ * DIM;
#pragma unroll
  for (int mi = 0; mi < 4; ++mi)
#pragma unroll
    for (int ni = 0; ni < 4; ++ni)
#pragma unroll
      for (int r = 0; r < 4; ++r) {
        int row = row0 + wm * 64 + mi * 16 + q * 4 + r;
        int col = col0 + wn * 64 + ni * 16 + lr;
        O[(size_t)row * DIM + col] = acc[mi][ni][r];
      }
}

__global__ __launch_bounds__(256) void o_reduce_kernel(const float* __restrict__ Op,
                                                       float* __restrict__ O) {
  const size_t N = (size_t)SEQ * DIM;
  size_t i = ((size_t)blockIdx.x * 256 + threadIdx.x) * 4;
  float4 a = *(const float4*)(Op + i);
  float4 b = *(const float4*)(Op + N + i);
  float4 c = *(const float4*)(Op + 2 * N + i);
  float4 d = *(const float4*)(Op + 3 * N + i);
  float4 r;
  r.x = (a.x + b.x) + (c.x + d.x);
  r.y = (a.y + b.y) + (c.y + d.y);
  r.z = (a.z + b.z) + (c.z + d.z);
  r.w = (a.w + b.w) + (c.w + d.w);
  *(float4*)(O + i) = r;
}

// ---------- launch ----------
extern "C" void kernel_launch(void* const* d_in, const int* in_sizes, int n_in,
                              void* d_out, int out_size, void* d_ws, size_t ws_size,
                              hipStream_t stream) {
  const float* X = (const float*)d_in[0];
  const float* Wq = (const float*)d_in[1];
  const float* Wk = (const float*)d_in[2];
  const float* Wv = (const float*)d_in[3];

  const size_t MB = 1024 * 1024;
  char* w = (char*)d_ws;
  u16* Xh = (u16*)(w + 0 * MB);    // 8 MB
  u16* Xl = (u16*)(w + 8 * MB);    // 8 MB
  u16* WqhT = (u16*)(w + 16 * MB); // 2 MB each
  u16* WqlT = (u16*)(w + 18 * MB);
  u16* WkhT = (u16*)(w + 20 * MB);
  u16* WklT = (u16*)(w + 22 * MB);
  u16* WvhT = (u16*)(w + 24 * MB);
  u16* Qh = (u16*)(w + 26 * MB);   // 8 MB each
  u16* Ql = (u16*)(w + 34 * MB);
  u16* Kh = (u16*)(w + 42 * MB);
  u16* Kl = (u16*)(w + 50 * MB);
  u16* VT = (u16*)(w + 58 * MB);   // 8 MB
  float* S = (float*)(w + 66 * MB);    // 64 MB
  u16* P = (u16*)(w + 26 * MB);        // aliases Qh..Kl (dead after s_kernel)
  float* Opart = (float*)(w + 66 * MB);// aliases S (dead after softmax), 64 MB
  // total: 130 MB

  split_x_kernel<<<(SEQ * DIM) / (256 * 4), 256, 0, stream>>>(X, Xh, Xl);
  split_w_t_kernel<<<dim3(32, 32, 3), dim3(32, 8), 0, stream>>>(
      Wq, Wk, Wv, WqhT, WqlT, WkhT, WklT, WvhT);
  qkv_kernel<<<dim3(DIM / 128, SEQ / 128, 3), 256, 0, stream>>>(
      Xh, Xl, WqhT, WqlT, WkhT, WklT, WvhT, Qh, Ql, Kh, Kl, VT);
  s_kernel<<<dim3(SEQ / 128, SEQ / 128), 256, 0, stream>>>(Qh, Ql, Kh, Kl, S);
  softmax_kernel<<<SEQ, 256, 0, stream>>>(S, P);
  o_kernel<<<dim3(DIM / 128, SEQ / 128, 4), 256, 0, stream>>>(P, VT, Opart);
  o_reduce_kernel<<<(SEQ * DIM) / (256 * 4), 256, 0, stream>>>(Opart, (float*)d_out);
}